// Round 7
// baseline (487.997 us; speedup 1.0000x reference)
//
#include <hip/hip_runtime.h>

// B=8, T=4096, D=256, H=8, K=1024, DH=32
#define BB 8
#define TT 4096
#define DD 256
#define HH 8
#define KK 1024
#define DHH 32
#define Q_ELEMS ((size_t)BB * TT * DD)   // 8388608 quantize floats
// out layout: [quantize Q_ELEMS][commit_loss 1][embed_ind B*T*H as float]

typedef float f32x4 __attribute__((ext_vector_type(4)));

// Precompute |e|^2 per (head, code): EXACT same sequential-fmaf order as round 1
// (which matched np argmax on all 262144 decisions, absmax 0.0).
__global__ void ee_kernel(const float* __restrict__ embeds, float* __restrict__ ee) {
    int i = blockIdx.x * blockDim.x + threadIdx.x;   // 0 .. H*K-1
    if (i < HH * KK) {
        const float* e = embeds + (size_t)i * DHH;
        float s = 0.f;
#pragma unroll
        for (int d = 0; d < DHH; ++d) s = fmaf(e[d], e[d], s);
        ee[i] = s;
    }
}

// One wave = 64 consecutive tokens x 1 head. x chunk pinned in VGPRs (asm
// barrier prevents the round-1 rematerialization that caused 20.6 GB of
// refetch); embeds row is wave-uniform -> scalar s_load broadcast.
__global__ __launch_bounds__(256) void vq_exact(const float* __restrict__ x,
                                                const float* __restrict__ embeds,
                                                const float* __restrict__ ee,
                                                float* __restrict__ out) {
    int g = blockIdx.x * 256 + threadIdx.x;
    int lane = threadIdx.x & 63;
    int wave = g >> 6;                 // 0 .. 4095
    int head = __builtin_amdgcn_readfirstlane(wave & (HH - 1));  // wave-uniform
    int tk = (wave >> 3) * 64 + lane;  // token 0..32767

    // Load this lane's 32 x floats once; pin them in VGPRs.
    const float* xr = x + (size_t)tk * DD + head * DHH;
    float xv[DHH];
#pragma unroll
    for (int d = 0; d < DHH; d += 4) *(f32x4*)&xv[d] = *(const f32x4*)(xr + d);
    asm volatile("" : "+v"(xv[0]),  "+v"(xv[1]),  "+v"(xv[2]),  "+v"(xv[3]),
                      "+v"(xv[4]),  "+v"(xv[5]),  "+v"(xv[6]),  "+v"(xv[7]),
                      "+v"(xv[8]),  "+v"(xv[9]),  "+v"(xv[10]), "+v"(xv[11]),
                      "+v"(xv[12]), "+v"(xv[13]), "+v"(xv[14]), "+v"(xv[15]),
                      "+v"(xv[16]), "+v"(xv[17]), "+v"(xv[18]), "+v"(xv[19]),
                      "+v"(xv[20]), "+v"(xv[21]), "+v"(xv[22]), "+v"(xv[23]),
                      "+v"(xv[24]), "+v"(xv[25]), "+v"(xv[26]), "+v"(xv[27]),
                      "+v"(xv[28]), "+v"(xv[29]), "+v"(xv[30]), "+v"(xv[31]));

    const float* eh  = embeds + (size_t)head * KK * DHH;  // wave-uniform
    const float* eeh = ee + head * KK;                    // wave-uniform

    float best = -3.4e38f;
    int bestk = 0;
#pragma unroll 2
    for (int k = 0; k < KK; ++k) {
        const float* er = eh + (size_t)k * DHH;   // wave-uniform -> s_load
        float dot = 0.f;
#pragma unroll
        for (int d = 0; d < DHH; ++d) dot = fmaf(er[d], xv[d], dot);
        float score = 2.f * dot - eeh[k];         // identical expression to round 1
        if (score > best) { best = score; bestk = k; }   // strict > = first occurrence
    }

    // Gather winning code row -> quantize (exact fp32 embeds).
    float* q = out + (size_t)tk * DD + head * DHH;
    const float* win = eh + (size_t)bestk * DHH;
#pragma unroll
    for (int d = 0; d < DHH; d += 4)
        *(f32x4*)(q + d) = *(const f32x4*)(win + d);

    // embed_ind as float (flat f32 out buffer).
    out[Q_ELEMS + 1 + (size_t)tk * HH + head] = (float)bestk;

    // commit_loss scalar = 0.0
    if (g == 0) out[Q_ELEMS] = 0.0f;
}

extern "C" void kernel_launch(void* const* d_in, const int* in_sizes, int n_in,
                              void* d_out, int out_size, void* d_ws, size_t ws_size,
                              hipStream_t stream) {
    const float* x      = (const float*)d_in[0];
    // d_in[1] = x_len (unused by reference forward)
    const float* embeds = (const float*)d_in[2];
    float* out = (float*)d_out;
    float* ee  = (float*)d_ws;   // 32 KB scratch for |e|^2 table

    ee_kernel<<<(HH * KK + 255) / 256, 256, 0, stream>>>(embeds, ee);

    int total_waves = BB * TT * HH / 64;            // 4096 waves
    int blocks = total_waves / 4;                   // 4 waves/block
    vq_exact<<<blocks, 256, 0, stream>>>(x, embeds, ee, out);
}

// Round 9
// 486.085 us; speedup vs baseline: 1.0039x; 1.0039x over previous
//
#include <hip/hip_runtime.h>

// B=8, T=4096, D=256, H=8, K=1024, DH=32
#define BB 8
#define TT 4096
#define DD 256
#define HH 8
#define KK 1024
#define DHH 32
#define Q_ELEMS ((size_t)BB * TT * DD)   // 8388608 quantize floats
// out layout: [quantize Q_ELEMS][commit_loss 1][embed_ind B*T*H as float]

typedef float f32x4 __attribute__((ext_vector_type(4)));

// Precompute |e|^2 per (head, code): EXACT same sequential-fmaf order as round 1
// (matched np argmax on all 262144 decisions, absmax 0.0).
__global__ void ee_kernel(const float* __restrict__ embeds, float* __restrict__ ee) {
    int i = blockIdx.x * blockDim.x + threadIdx.x;   // 0 .. H*K-1
    if (i < HH * KK) {
        const float* e = embeds + (size_t)i * DHH;
        float s = 0.f;
#pragma unroll
        for (int d = 0; d < DHH; ++d) s = fmaf(e[d], e[d], s);
        ee[i] = s;
    }
}

// One wave = 64 consecutive tokens x 1 head.
// x chunk in 8 NAMED f32x4 variables (static element accesses only -> SROA
// trivially keeps them in VGPRs; the round-1/7 float[32] array with punned
// stores lived in scratch -> 20.6 GB refetch, VGPR_Count=24).
// embeds row address is wave-uniform (readfirstlane'd head) -> s_load broadcast.
__global__ __launch_bounds__(256) void vq_exact(const float* __restrict__ x,
                                                const float* __restrict__ embeds,
                                                const float* __restrict__ ee,
                                                float* __restrict__ out) {
    int g = blockIdx.x * 256 + threadIdx.x;
    int lane = threadIdx.x & 63;
    int wave = g >> 6;                 // 0 .. 4095
    int head = __builtin_amdgcn_readfirstlane(wave & (HH - 1));  // wave-uniform
    int tk = (wave >> 3) * 64 + lane;  // token 0..32767

    const float* xr = x + (size_t)tk * DD + head * DHH;
    f32x4 xa = *(const f32x4*)(xr + 0);
    f32x4 xb = *(const f32x4*)(xr + 4);
    f32x4 xc = *(const f32x4*)(xr + 8);
    f32x4 xd = *(const f32x4*)(xr + 12);
    f32x4 xe = *(const f32x4*)(xr + 16);
    f32x4 xf = *(const f32x4*)(xr + 20);
    f32x4 xg = *(const f32x4*)(xr + 24);
    f32x4 xh = *(const f32x4*)(xr + 28);

    const float* eh  = embeds + (size_t)head * KK * DHH;  // wave-uniform
    const float* eeh = ee + head * KK;                    // wave-uniform

    float best = -3.4e38f;
    int bestk = 0;
#pragma unroll 2
    for (int k = 0; k < KK; ++k) {
        const float* er = eh + (size_t)k * DHH;   // wave-uniform -> s_load
        float dot = 0.f;
        // d = 0..31 strictly sequential — identical accumulation order to round 1.
        dot = fmaf(er[0],  xa.x, dot); dot = fmaf(er[1],  xa.y, dot);
        dot = fmaf(er[2],  xa.z, dot); dot = fmaf(er[3],  xa.w, dot);
        dot = fmaf(er[4],  xb.x, dot); dot = fmaf(er[5],  xb.y, dot);
        dot = fmaf(er[6],  xb.z, dot); dot = fmaf(er[7],  xb.w, dot);
        dot = fmaf(er[8],  xc.x, dot); dot = fmaf(er[9],  xc.y, dot);
        dot = fmaf(er[10], xc.z, dot); dot = fmaf(er[11], xc.w, dot);
        dot = fmaf(er[12], xd.x, dot); dot = fmaf(er[13], xd.y, dot);
        dot = fmaf(er[14], xd.z, dot); dot = fmaf(er[15], xd.w, dot);
        dot = fmaf(er[16], xe.x, dot); dot = fmaf(er[17], xe.y, dot);
        dot = fmaf(er[18], xe.z, dot); dot = fmaf(er[19], xe.w, dot);
        dot = fmaf(er[20], xf.x, dot); dot = fmaf(er[21], xf.y, dot);
        dot = fmaf(er[22], xf.z, dot); dot = fmaf(er[23], xf.w, dot);
        dot = fmaf(er[24], xg.x, dot); dot = fmaf(er[25], xg.y, dot);
        dot = fmaf(er[26], xg.z, dot); dot = fmaf(er[27], xg.w, dot);
        dot = fmaf(er[28], xh.x, dot); dot = fmaf(er[29], xh.y, dot);
        dot = fmaf(er[30], xh.z, dot); dot = fmaf(er[31], xh.w, dot);
        float score = 2.f * dot - eeh[k];         // identical expression to round 1
        if (score > best) { best = score; bestk = k; }   // strict > = first occurrence
    }

    // Gather winning code row -> quantize (exact fp32 embeds).
    float* q = out + (size_t)tk * DD + head * DHH;
    const float* win = eh + (size_t)bestk * DHH;
#pragma unroll
    for (int d = 0; d < DHH; d += 4)
        *(f32x4*)(q + d) = *(const f32x4*)(win + d);

    // embed_ind as float (flat f32 out buffer).
    out[Q_ELEMS + 1 + (size_t)tk * HH + head] = (float)bestk;

    // commit_loss scalar = 0.0
    if (g == 0) out[Q_ELEMS] = 0.0f;
}

extern "C" void kernel_launch(void* const* d_in, const int* in_sizes, int n_in,
                              void* d_out, int out_size, void* d_ws, size_t ws_size,
                              hipStream_t stream) {
    const float* x      = (const float*)d_in[0];
    // d_in[1] = x_len (unused by reference forward)
    const float* embeds = (const float*)d_in[2];
    float* out = (float*)d_out;
    float* ee  = (float*)d_ws;   // 32 KB scratch for |e|^2 table

    ee_kernel<<<(HH * KK + 255) / 256, 256, 0, stream>>>(embeds, ee);

    int total_waves = BB * TT * HH / 64;            // 4096 waves
    int blocks = total_waves / 4;                   // 4 waves/block
    vq_exact<<<blocks, 256, 0, stream>>>(x, embeds, ee, out);
}

// Round 10
// 478.613 us; speedup vs baseline: 1.0196x; 1.0156x over previous
//
#include <hip/hip_runtime.h>

// B=8, T=4096, D=256, H=8, K=1024, DH=32
#define BB 8
#define TT 4096
#define DD 256
#define HH 8
#define KK 1024
#define DHH 32
#define Q_ELEMS ((size_t)BB * TT * DD)   // 8388608 quantize floats
// out layout: [quantize Q_ELEMS][commit_loss 1][embed_ind B*T*H as float]

typedef float f32x4 __attribute__((ext_vector_type(4)));

// Precompute |e|^2 per (head, code): same sequential-fmaf order as the
// passing rounds (matched np argmax on all 262144 decisions, absmax 0.0).
__global__ void ee_kernel(const float* __restrict__ embeds, float* __restrict__ ee) {
    int i = blockIdx.x * blockDim.x + threadIdx.x;   // 0 .. H*K-1
    if (i < HH * KK) {
        const float* e = embeds + (size_t)i * DHH;
        float s = 0.f;
#pragma unroll
        for (int d = 0; d < DHH; ++d) s = fmaf(e[d], e[d], s);
        ee[i] = s;
    }
}

// One wave = 64 consecutive tokens x 1 head.
// Rounds 1/7/9 all showed VGPR_Count=24: the compiler SINKS the 8 x-loads
// into the k-loop (legal under __restrict__; RA prefers max-occupancy regs).
// Fix: (a) __launch_bounds__(256,4) — grid is only 16 waves/CU, so tell RA
// it may use up to ~128 VGPRs; (b) opaque asm pin on the 8 NAMED vector
// values — post-asm they are not provably equal to memory, so re-loading
// them inside the loop is illegal. Comparator is byte-identical to the
// passing rounds.
__global__ __launch_bounds__(256, 4) void vq_exact(const float* __restrict__ x,
                                                   const float* __restrict__ embeds,
                                                   const float* __restrict__ ee,
                                                   float* __restrict__ out) {
    int g = blockIdx.x * 256 + threadIdx.x;
    int lane = threadIdx.x & 63;
    int wave = g >> 6;                 // 0 .. 4095
    int head = __builtin_amdgcn_readfirstlane(wave & (HH - 1));  // wave-uniform
    int tk = (wave >> 3) * 64 + lane;  // token 0..32767

    const float* xr = x + (size_t)tk * DD + head * DHH;
    f32x4 xa = *(const f32x4*)(xr + 0);
    f32x4 xb = *(const f32x4*)(xr + 4);
    f32x4 xc = *(const f32x4*)(xr + 8);
    f32x4 xd = *(const f32x4*)(xr + 12);
    f32x4 xe = *(const f32x4*)(xr + 16);
    f32x4 xf = *(const f32x4*)(xr + 20);
    f32x4 xg = *(const f32x4*)(xr + 24);
    f32x4 xh = *(const f32x4*)(xr + 28);
    // Opaque pin: values become asm-defined -> cannot be rematerialized as loads.
    asm volatile("" : "+v"(xa), "+v"(xb), "+v"(xc), "+v"(xd),
                      "+v"(xe), "+v"(xf), "+v"(xg), "+v"(xh));

    const float* eh  = embeds + (size_t)head * KK * DHH;  // wave-uniform
    const float* eeh = ee + head * KK;                    // wave-uniform

    float best = -3.4e38f;
    int bestk = 0;
#pragma unroll 2
    for (int k = 0; k < KK; ++k) {
        const float* er = eh + (size_t)k * DHH;   // wave-uniform -> s_load
        float dot = 0.f;
        // d = 0..31 strictly sequential — identical accumulation order to round 1.
        dot = fmaf(er[0],  xa.x, dot); dot = fmaf(er[1],  xa.y, dot);
        dot = fmaf(er[2],  xa.z, dot); dot = fmaf(er[3],  xa.w, dot);
        dot = fmaf(er[4],  xb.x, dot); dot = fmaf(er[5],  xb.y, dot);
        dot = fmaf(er[6],  xb.z, dot); dot = fmaf(er[7],  xb.w, dot);
        dot = fmaf(er[8],  xc.x, dot); dot = fmaf(er[9],  xc.y, dot);
        dot = fmaf(er[10], xc.z, dot); dot = fmaf(er[11], xc.w, dot);
        dot = fmaf(er[12], xd.x, dot); dot = fmaf(er[13], xd.y, dot);
        dot = fmaf(er[14], xd.z, dot); dot = fmaf(er[15], xd.w, dot);
        dot = fmaf(er[16], xe.x, dot); dot = fmaf(er[17], xe.y, dot);
        dot = fmaf(er[18], xe.z, dot); dot = fmaf(er[19], xe.w, dot);
        dot = fmaf(er[20], xf.x, dot); dot = fmaf(er[21], xf.y, dot);
        dot = fmaf(er[22], xf.z, dot); dot = fmaf(er[23], xf.w, dot);
        dot = fmaf(er[24], xg.x, dot); dot = fmaf(er[25], xg.y, dot);
        dot = fmaf(er[26], xg.z, dot); dot = fmaf(er[27], xg.w, dot);
        dot = fmaf(er[28], xh.x, dot); dot = fmaf(er[29], xh.y, dot);
        dot = fmaf(er[30], xh.z, dot); dot = fmaf(er[31], xh.w, dot);
        float score = 2.f * dot - eeh[k];         // identical expression to round 1
        if (score > best) { best = score; bestk = k; }   // strict > = first occurrence
    }

    // Gather winning code row -> quantize (exact fp32 embeds).
    float* q = out + (size_t)tk * DD + head * DHH;
    const float* win = eh + (size_t)bestk * DHH;
#pragma unroll
    for (int d = 0; d < DHH; d += 4)
        *(f32x4*)(q + d) = *(const f32x4*)(win + d);

    // embed_ind as float (flat f32 out buffer).
    out[Q_ELEMS + 1 + (size_t)tk * HH + head] = (float)bestk;

    // commit_loss scalar = 0.0
    if (g == 0) out[Q_ELEMS] = 0.0f;
}

extern "C" void kernel_launch(void* const* d_in, const int* in_sizes, int n_in,
                              void* d_out, int out_size, void* d_ws, size_t ws_size,
                              hipStream_t stream) {
    const float* x      = (const float*)d_in[0];
    // d_in[1] = x_len (unused by reference forward)
    const float* embeds = (const float*)d_in[2];
    float* out = (float*)d_out;
    float* ee  = (float*)d_ws;   // 32 KB scratch for |e|^2 table

    ee_kernel<<<(HH * KK + 255) / 256, 256, 0, stream>>>(embeds, ee);

    int total_waves = BB * TT * HH / 64;            // 4096 waves
    int blocks = total_waves / 4;                   // 4 waves/block
    vq_exact<<<blocks, 256, 0, stream>>>(x, embeds, ee, out);
}

// Round 11
// 384.102 us; speedup vs baseline: 1.2705x; 1.2461x over previous
//
#include <hip/hip_runtime.h>

// B=8, T=4096, D=256, H=8, K=1024, DH=32
#define BB 8
#define TT 4096
#define DD 256
#define HH 8
#define KK 1024
#define DHH 32
#define NTOK (BB * TT)                 // 32768 tokens
#define NITEM (NTOK * HH)              // 262144 (token, head) items
#define Q_ELEMS ((size_t)BB * TT * DD) // 8388608 quantize floats
// out layout: [quantize Q_ELEMS][commit_loss 1][embed_ind B*T*H as float]

typedef float f32x4 __attribute__((ext_vector_type(4)));

// d_ws layout: [0, 32KB) = |e|^2 table; [32KB, 32KB + 4MB) = partials,
// one uint4 per item = {b0_bits, k0, b1_bits, k1} (halves write uint2 each).
#define WS_PARTS_OFF 32768

// |e|^2 per (head, code) — same sequential-fmaf order as all passing rounds
// (matched np argmax on all 262144 decisions, absmax 0.0, four times).
__global__ void ee_kernel(const float* __restrict__ embeds, float* __restrict__ ee) {
    int i = blockIdx.x * blockDim.x + threadIdx.x;   // 0 .. H*K-1
    if (i < HH * KK) {
        const float* e = embeds + (size_t)i * DHH;
        float s = 0.f;
#pragma unroll
        for (int d = 0; d < DHH; ++d) s = fmaf(e[d], e[d], s);
        ee[i] = s;
    }
}

// One wave = 64 consecutive tokens x 1 head x ONE HALF of the codebook.
// Grid 2048 blocks -> 8 blocks/CU -> 8 waves/SIMD: at 62% VALUBusy the
// measured stall model (busy = N*72/(72+L), L~390cy) predicts saturation.
// Comparator (fmaf chain, 2*dot-ee, strict >) is byte-identical per code;
// split + merge reproduces full-scan first-occurrence argmax exactly.
__global__ __launch_bounds__(256, 8) void vq_split(const float* __restrict__ x,
                                                   const float* __restrict__ embeds,
                                                   const float* __restrict__ ee,
                                                   uint2* __restrict__ parts2) {
    int g = blockIdx.x * 256 + threadIdx.x;
    int lane = threadIdx.x & 63;
    int W = g >> 6;                    // 0 .. 8191
    int half = W & 1;
    int R = W >> 1;                    // 0 .. 4095 (same decomposition as before)
    int head = __builtin_amdgcn_readfirstlane(R & (HH - 1));
    int half_u = __builtin_amdgcn_readfirstlane(half);
    int tk = (R >> 3) * 64 + lane;     // token 0..32767

    const float* xr = x + (size_t)tk * DD + head * DHH;
    f32x4 xa = *(const f32x4*)(xr + 0);
    f32x4 xb = *(const f32x4*)(xr + 4);
    f32x4 xc = *(const f32x4*)(xr + 8);
    f32x4 xd = *(const f32x4*)(xr + 12);
    f32x4 xe = *(const f32x4*)(xr + 16);
    f32x4 xf = *(const f32x4*)(xr + 20);
    f32x4 xg = *(const f32x4*)(xr + 24);
    f32x4 xh = *(const f32x4*)(xr + 28);

    const float* eh  = embeds + (size_t)head * KK * DHH;  // wave-uniform
    const float* eeh = ee + head * KK;                    // wave-uniform
    const int k0 = half_u * (KK / 2);                     // wave-uniform

    float best = -3.4e38f;
    int bestk = k0;
#pragma unroll 2
    for (int kk = 0; kk < KK / 2; ++kk) {
        int k = k0 + kk;
        const float* er = eh + (size_t)k * DHH;   // wave-uniform -> s_load
        float dot = 0.f;
        // d = 0..31 strictly sequential — identical accumulation order to round 1.
        dot = fmaf(er[0],  xa.x, dot); dot = fmaf(er[1],  xa.y, dot);
        dot = fmaf(er[2],  xa.z, dot); dot = fmaf(er[3],  xa.w, dot);
        dot = fmaf(er[4],  xb.x, dot); dot = fmaf(er[5],  xb.y, dot);
        dot = fmaf(er[6],  xb.z, dot); dot = fmaf(er[7],  xb.w, dot);
        dot = fmaf(er[8],  xc.x, dot); dot = fmaf(er[9],  xc.y, dot);
        dot = fmaf(er[10], xc.z, dot); dot = fmaf(er[11], xc.w, dot);
        dot = fmaf(er[12], xd.x, dot); dot = fmaf(er[13], xd.y, dot);
        dot = fmaf(er[14], xd.z, dot); dot = fmaf(er[15], xd.w, dot);
        dot = fmaf(er[16], xe.x, dot); dot = fmaf(er[17], xe.y, dot);
        dot = fmaf(er[18], xe.z, dot); dot = fmaf(er[19], xe.w, dot);
        dot = fmaf(er[20], xf.x, dot); dot = fmaf(er[21], xf.y, dot);
        dot = fmaf(er[22], xf.z, dot); dot = fmaf(er[23], xf.w, dot);
        dot = fmaf(er[24], xg.x, dot); dot = fmaf(er[25], xg.y, dot);
        dot = fmaf(er[26], xg.z, dot); dot = fmaf(er[27], xg.w, dot);
        dot = fmaf(er[28], xh.x, dot); dot = fmaf(er[29], xh.y, dot);
        dot = fmaf(er[30], xh.z, dot); dot = fmaf(er[31], xh.w, dot);
        float score = 2.f * dot - eeh[k];         // identical expression to round 1
        if (score > best) { best = score; bestk = k; }   // strict > = first occurrence
    }

    // Exact partial result for this half: 8 B per (item, half).
    int item = tk * HH + head;
    uint2 r;
    r.x = __float_as_uint(best);
    r.y = (unsigned)bestk;
    parts2[(size_t)item * 2 + half_u] = r;
}

// Merge halves (exact scores -> decision identical to full scan) + gather.
// 8 lanes per item; 32 items per 256-thread block.
__global__ __launch_bounds__(256) void vq_merge(const float* __restrict__ embeds,
                                                const uint4* __restrict__ parts,
                                                float* __restrict__ out) {
    int tid = threadIdx.x;
    int item = blockIdx.x * 32 + (tid >> 3);   // 0 .. NITEM-1
    int sl = tid & 7;

    uint4 p = parts[item];
    float b0 = __uint_as_float(p.x); int k0 = (int)p.y;
    float b1 = __uint_as_float(p.z); int k1 = (int)p.w;
    // Lower half wins ties (k0 < k1 always) => first-occurrence argmax.
    int kw = (b1 > b0) ? k1 : k0;

    int t = item >> 3;          // token
    int h = item & 7;           // head

    const float* win = embeds + ((size_t)h * KK + kw) * DHH;
    f32x4 q = *(const f32x4*)(win + sl * 4);
    *(f32x4*)(out + (size_t)t * DD + h * DHH + sl * 4) = q;

    if (sl == 0) out[Q_ELEMS + 1 + item] = (float)kw;     // embed_ind
    if (item == 0 && sl == 0) out[Q_ELEMS] = 0.0f;        // commit_loss
}

extern "C" void kernel_launch(void* const* d_in, const int* in_sizes, int n_in,
                              void* d_out, int out_size, void* d_ws, size_t ws_size,
                              hipStream_t stream) {
    const float* x      = (const float*)d_in[0];
    // d_in[1] = x_len (unused by reference forward)
    const float* embeds = (const float*)d_in[2];
    float* out = (float*)d_out;

    float* ee    = (float*)d_ws;                                  // 32 KB
    uint2* parts = (uint2*)((char*)d_ws + WS_PARTS_OFF);          // 4 MB

    ee_kernel<<<(HH * KK + 255) / 256, 256, 0, stream>>>(embeds, ee);

    // 8192 waves (2 halves x 4096) / 4 waves per block = 2048 blocks
    vq_split<<<2048, 256, 0, stream>>>(x, embeds, ee, parts);

    // 262144 items / 32 per block = 8192 blocks
    vq_merge<<<8192, 256, 0, stream>>>(embeds, (const uint4*)parts, out);
}